// Round 2
// baseline (135.961 us; speedup 1.0000x reference)
//
#include <hip/hip_runtime.h>

#define NT 2000
#define NB 256
#define NF 5
#define NS 500
#define LOG0   (-1e30f)
#define LOG2E  1.44269504088896340736f
#define LN2F   0.69314718055994530942f
#define RSTRIDE 2024   // wtabT row stride: >=2000, %4==0 (b128 align), %32==8 (banks disjoint)

// One block per batch. 4 waves; wave w spans states [128w-64, 128w+127]:
// 64 left-halo (recomputed redundantly) + 128 owned. Lane L holds 3 adjacent
// states rel=3L..3L+2. Exp-domain recurrence p[s] += p[s-1]*w_t[idx[s]] with
// PER-LANE log2 scale Lw. Cross-lane handoff via DPP wave_shr:1.
// adj = 2^(Lw_left-Lw_self) folded into the W0 operand off the dependent path.
// Per-lane renorm every 16 steps; cross-wave exchange every 64 steps.
//
// R2: register double-buffer of the weight stream. At VGPR=52 the compiler
// could not hoist a chunk's 12 float4 LDS loads; with 1 wave/SIMD every
// exposed lgkmcnt wait (~100 cy) hit the serial chain. Now chunk c+1's 12
// ds_read_b128 are issued before chunk c's 16 steps of compute (named regs,
// parity swap -> no dynamic indexing / scratch). Also XCD-swizzle the
// batch id so 32 consecutive b share one XCD L2 (x rows share 64B lines
// across b -> dedup the 3.5x over-fetch).
__device__ __forceinline__ float wave_shr1(float v) {
    // DPP wave_shr:1 (0x138): lane i reads lane i-1; bound_ctrl=1 -> lane 0 = 0.
    return __int_as_float(
        __builtin_amdgcn_mov_dpp(__float_as_int(v), 0x138, 0xf, 0xf, true));
}

__global__ __launch_bounds__(256, 1) void ctc_fwd_kernel(
    const float* __restrict__ x,        // (NT, NB, NF)
    const int*   __restrict__ seqs,     // (NB, NS)
    const int*   __restrict__ seqlens,  // (NB,)
    float*       __restrict__ out)      // (NB,)
{
    __shared__ __align__(16) float wtabT[4 * RSTRIDE];  // w[i][t] = exp(x_t[i]-x_t[4])
    __shared__ float Gbuf[576];                         // log2-domain exchange, idx = 64+s
    __shared__ float red[256];                          // stay-sum reduction

    // XCD-aware batch swizzle: hw round-robins blockIdx%8 across XCDs;
    // map so XCD k handles contiguous b in [32k, 32k+32) for L2 line sharing.
    const int b    = ((blockIdx.x & 7) << 5) | (blockIdx.x >> 3);
    const int tid  = threadIdx.x;
    const int wave = tid >> 6;
    const int lane = tid & 63;

    // ---------------- precompute: transposed weights + stay sum ----------------
    float csum = 0.f;
    for (int t = tid; t < NT; t += 256) {
        const float* xp = x + (size_t)t * (NB * NF) + b * NF;
        const float x4 = xp[4];
        wtabT[0 * RSTRIDE + t] = __builtin_amdgcn_exp2f((xp[0] - x4) * LOG2E);
        wtabT[1 * RSTRIDE + t] = __builtin_amdgcn_exp2f((xp[1] - x4) * LOG2E);
        wtabT[2 * RSTRIDE + t] = __builtin_amdgcn_exp2f((xp[2] - x4) * LOG2E);
        wtabT[3 * RSTRIDE + t] = __builtin_amdgcn_exp2f((xp[3] - x4) * LOG2E);
        csum += x4;
    }
    for (int i = tid; i < 576; i += 256) Gbuf[i] = LOG0;
    red[tid] = csum;
    __syncthreads();
    for (int off = 128; off > 0; off >>= 1) {
        if (tid < off) red[tid] += red[tid + off];
        __syncthreads();
    }
    // red[0] = C = sum over t of x_t[4]

    // ---------------- per-lane setup ----------------
    const int wbase = wave * 128 - 64;
    const int rel0 = 3 * lane;
    const int s0 = wbase + rel0, s1 = s0 + 1, s2 = s0 + 2;

    const int i0 = (s0 >= 1 && s0 <= NS) ? seqs[b * NS + s0 - 1] : 0;
    const int i1 = (s1 >= 1 && s1 <= NS) ? seqs[b * NS + s1 - 1] : 0;
    const int i2 = (s2 >= 1 && s2 <= NS) ? seqs[b * NS + s2 - 1] : 0;
    const float* wrow0 = &wtabT[i0 * RSTRIDE];
    const float* wrow1 = &wtabT[i1 * RSTRIDE];
    const float* wrow2 = &wtabT[i2 * RSTRIDE];

    float p0 = (s0 == 0) ? 1.f : 0.f;
    float p1 = (s1 == 0) ? 1.f : 0.f;
    float p2 = (s2 == 0) ? 1.f : 0.f;
    float Lw  = 0.f;   // per-lane log2 offset
    float adj = 1.f;   // 2^(Lw_left - Lw_self), refreshed after every renorm/exchange

    // W0A already contains the adj factor (folded off the dependent chain).
#define STEP(W0A, W1, W2) do {                \
        const float sh = wave_shr1(p2);       \
        p2 = fmaf(p1, (W2), p2);              \
        p1 = fmaf(p0, (W1), p1);              \
        p0 = fmaf(sh, (W0A), p0);             \
    } while (0)

    // Double-buffered weight registers: 2 x 12 float4 (named, static indexing).
    float4 Xa0, Xa1, Xa2, Xa3, Xb0, Xb1, Xb2, Xb3, Xc0, Xc1, Xc2, Xc3;
    float4 Ya0, Ya1, Ya2, Ya3, Yb0, Yb1, Yb2, Yb3, Yc0, Yc1, Yc2, Yc3;

#define PRELOAD(P, TB) do {                                            \
        const int _tb = (TB);                                          \
        P##a0 = *reinterpret_cast<const float4*>(wrow0 + _tb);         \
        P##a1 = *reinterpret_cast<const float4*>(wrow0 + _tb + 4);     \
        P##a2 = *reinterpret_cast<const float4*>(wrow0 + _tb + 8);     \
        P##a3 = *reinterpret_cast<const float4*>(wrow0 + _tb + 12);    \
        P##b0 = *reinterpret_cast<const float4*>(wrow1 + _tb);         \
        P##b1 = *reinterpret_cast<const float4*>(wrow1 + _tb + 4);     \
        P##b2 = *reinterpret_cast<const float4*>(wrow1 + _tb + 8);     \
        P##b3 = *reinterpret_cast<const float4*>(wrow1 + _tb + 12);    \
        P##c0 = *reinterpret_cast<const float4*>(wrow2 + _tb);         \
        P##c1 = *reinterpret_cast<const float4*>(wrow2 + _tb + 4);     \
        P##c2 = *reinterpret_cast<const float4*>(wrow2 + _tb + 8);     \
        P##c3 = *reinterpret_cast<const float4*>(wrow2 + _tb + 12);    \
    } while (0)

#define QSTEP(WA, WB, WC) do {                \
        STEP(WA.x * adj, WB.x, WC.x);         \
        STEP(WA.y * adj, WB.y, WC.y);         \
        STEP(WA.z * adj, WB.z, WC.z);         \
        STEP(WA.w * adj, WB.w, WC.w);         \
    } while (0)

#define COMPUTE(P) do {                       \
        QSTEP(P##a0, P##b0, P##c0);           \
        QSTEP(P##a1, P##b1, P##c1);           \
        QSTEP(P##a2, P##b2, P##c2);           \
        QSTEP(P##a3, P##b3, P##c3);           \
    } while (0)

    // ---------------- main loop: 125 chunks of 16 steps ----------------
    PRELOAD(X, 0);
    for (int c = 0; c < 125; ++c) {
        if (c > 0) {
            if ((c & 3) == 0) {
                // ---- cross-wave exchange every 64 steps (log2 domain) ----
                __syncthreads();
                if (rel0     >= 64) Gbuf[64 + s0] = (p0 > 0.f) ? __builtin_amdgcn_logf(p0) + Lw : LOG0;
                if (rel0 + 1 >= 64) Gbuf[64 + s1] = (p1 > 0.f) ? __builtin_amdgcn_logf(p1) + Lw : LOG0;
                if (rel0 + 2 >= 64) Gbuf[64 + s2] = (p2 > 0.f) ? __builtin_amdgcn_logf(p2) + Lw : LOG0;
                __syncthreads();
                const float g0 = Gbuf[64 + s0];
                const float g1 = Gbuf[64 + s1];
                const float g2 = Gbuf[64 + s2];
                const float ref = fmaxf(fmaxf(g0, g1), g2);
                const bool alive = (ref > 0.5f * LOG0);
                // live states form a prefix of the window -> last live lane is
                // nearest-live-left for all dead lanes. Uniform mask -> scalar ops.
                const unsigned long long mk = __ballot(alive);
                float fb = 0.f;
                if (mk) {
                    const int lastlive = 63 - __builtin_clzll(mk);
                    fb = __int_as_float(
                        __builtin_amdgcn_readlane(__float_as_int(ref), lastlive));
                }
                Lw = alive ? ref : fb;
                p0 = __builtin_amdgcn_exp2f(g0 - Lw);   // dead: exp2(-1e30)=0
                p1 = __builtin_amdgcn_exp2f(g1 - Lw);
                p2 = __builtin_amdgcn_exp2f(g2 - Lw);
            } else {
                // ---- per-lane renorm every 16 steps ----
                const float m = fmaxf(fmaxf(p0, p1), p2);
                if (m > 0.f) {
                    const float inv = __builtin_amdgcn_rcpf(m);
                    Lw += __builtin_amdgcn_logf(m);     // v_log_f32 = log2
                    p0 *= inv; p1 *= inv; p2 *= inv;
                }
            }
            const float Lwp = wave_shr1(Lw);            // lane 0: Lwp=0; its sh inflow is 0 anyway
            adj = __builtin_amdgcn_exp2f(fminf(Lwp - Lw, 100.f));
        }
        // Issue next chunk's LDS loads, then compute current chunk from regs:
        // the lgkmcnt wait for c+1 hides behind 16 steps of compute.
        if ((c & 1) == 0) {
            if (c < 124) PRELOAD(Y, (c + 1) << 4);
            COMPUTE(X);
        } else {
            if (c < 124) PRELOAD(X, (c + 1) << 4);
            COMPUTE(Y);
        }
    }
#undef COMPUTE
#undef QSTEP
#undef PRELOAD
#undef STEP

    // ---------------- final write-out ----------------
    __syncthreads();
    if (rel0     >= 64) Gbuf[64 + s0] = (p0 > 0.f) ? __builtin_amdgcn_logf(p0) + Lw : LOG0;
    if (rel0 + 1 >= 64) Gbuf[64 + s1] = (p1 > 0.f) ? __builtin_amdgcn_logf(p1) + Lw : LOG0;
    if (rel0 + 2 >= 64) Gbuf[64 + s2] = (p2 > 0.f) ? __builtin_amdgcn_logf(p2) + Lw : LOG0;
    __syncthreads();
    if (tid == 0) {
        const int sl = seqlens[b];
        out[b] = -(Gbuf[64 + sl] * LN2F + red[0]) * (1.0f / (float)NT);
    }
}

extern "C" void kernel_launch(void* const* d_in, const int* in_sizes, int n_in,
                              void* d_out, int out_size, void* d_ws, size_t ws_size,
                              hipStream_t stream) {
    const float* x       = (const float*)d_in[0];
    const int*   seqs    = (const int*)d_in[1];
    const int*   seqlens = (const int*)d_in[2];
    float*       out     = (float*)d_out;

    ctc_fwd_kernel<<<dim3(NB), dim3(256), 0, stream>>>(x, seqs, seqlens, out);
}

// Round 3
// 119.615 us; speedup vs baseline: 1.1366x; 1.1366x over previous
//
#include <hip/hip_runtime.h>

#define NT 2000
#define NB 256
#define NF 5
#define NS 500
#define LOG0   (-1e30f)
#define LOG2E  1.44269504088896340736f
#define LN2F   0.69314718055994530942f
#define RSTRIDE 2024   // wtabT row stride: >=2000, %4==0 (b128 align), %32==8 (banks disjoint)

// One block per batch, 512 threads = 8 waves, 2 states/lane.
// Wave w spans states [64w-64, 64w+127]: lanes 0-31 = 64-state left halo
// (recomputed redundantly), lanes 32-63 = 64 owned states. 8 waves x 64
// owned = 512 >= 501 states. Halo depth 64 = exchange period 64 (info moves
// right 1 state/step), identical correctness argument to the 4-wave layout.
//
// WHY 8 waves: rocprof showed Occupancy = 1 wave/SIMD -> every latency
// (fma chain, DPP hazard, LDS round trip, trans ops) fully exposed
// (~78 cy/step vs ~12 cy issue). 2 waves/SIMD lets the hardware fill one
// wave's stalls with the other wave's issue. Per-lane work also drops to
// 2 fma + 1 DPP + 1 mul per step, and chunk loads to 8 float4 (2 rows),
// so VGPR pressure is back where the compiler hoists them (R2's 2x48-reg
// double-buffer overflowed the allocator and de-pipelined -> reverted).
//
// Exp-domain recurrence p[s] += p[s-1]*w_t[idx[s]] with PER-LANE log2
// scale Lw. Cross-lane handoff via DPP wave_shr:1 (lane 0 gets 0).
// adj = 2^(Lw_left-Lw_self) folded into the W0 operand off the chain.
// Per-lane renorm every 16 steps; cross-wave exchange (log2 via Gbuf)
// every 64 steps. XCD-swizzled batch id keeps the preamble gather dedup'd
// in per-XCD L2 (FETCH 36MB -> 5.3MB, R2-verified).
__device__ __forceinline__ float wave_shr1(float v) {
    // DPP wave_shr:1 (0x138): lane i reads lane i-1; bound_ctrl=1 -> lane 0 = 0.
    return __int_as_float(
        __builtin_amdgcn_mov_dpp(__float_as_int(v), 0x138, 0xf, 0xf, true));
}

__global__ __launch_bounds__(512, 1) void ctc_fwd_kernel(
    const float* __restrict__ x,        // (NT, NB, NF)
    const int*   __restrict__ seqs,     // (NB, NS)
    const int*   __restrict__ seqlens,  // (NB,)
    float*       __restrict__ out)      // (NB,)
{
    __shared__ __align__(16) float wtabT[4 * RSTRIDE];  // w[i][t] = exp(x_t[i]-x_t[4])
    __shared__ float Gbuf[576];                         // log2-domain exchange, idx = 64+s
    __shared__ float red[512];                          // stay-sum reduction

    // XCD-aware batch swizzle: hw round-robins blockIdx%8 across XCDs;
    // map so XCD k handles contiguous b in [32k, 32k+32) for L2 line sharing.
    const int b    = ((blockIdx.x & 7) << 5) | (blockIdx.x >> 3);
    const int tid  = threadIdx.x;
    const int wave = tid >> 6;
    const int lane = tid & 63;

    // ---------------- precompute: transposed weights + stay sum ----------------
    float csum = 0.f;
    for (int t = tid; t < NT; t += 512) {
        const float* xp = x + (size_t)t * (NB * NF) + b * NF;
        const float x4 = xp[4];
        wtabT[0 * RSTRIDE + t] = __builtin_amdgcn_exp2f((xp[0] - x4) * LOG2E);
        wtabT[1 * RSTRIDE + t] = __builtin_amdgcn_exp2f((xp[1] - x4) * LOG2E);
        wtabT[2 * RSTRIDE + t] = __builtin_amdgcn_exp2f((xp[2] - x4) * LOG2E);
        wtabT[3 * RSTRIDE + t] = __builtin_amdgcn_exp2f((xp[3] - x4) * LOG2E);
        csum += x4;
    }
    for (int i = tid; i < 576; i += 512) Gbuf[i] = LOG0;
    red[tid] = csum;
    __syncthreads();
    for (int off = 256; off > 0; off >>= 1) {
        if (tid < off) red[tid] += red[tid + off];
        __syncthreads();
    }
    // red[0] = C = sum over t of x_t[4]

    // ---------------- per-lane setup ----------------
    const int wbase = wave * 64 - 64;
    const int rel0 = 2 * lane;                 // 0..126; owned iff rel0 >= 64
    const int s0 = wbase + rel0, s1 = s0 + 1;
    const bool owned = (rel0 >= 64);

    const int i0 = (s0 >= 1 && s0 <= NS) ? seqs[b * NS + s0 - 1] : 0;
    const int i1 = (s1 >= 1 && s1 <= NS) ? seqs[b * NS + s1 - 1] : 0;
    const float* wrow0 = &wtabT[i0 * RSTRIDE];
    const float* wrow1 = &wtabT[i1 * RSTRIDE];

    float p0 = (s0 == 0) ? 1.f : 0.f;
    float p1 = (s1 == 0) ? 1.f : 0.f;
    float Lw  = 0.f;   // per-lane log2 offset
    float adj = 1.f;   // 2^(Lw_left - Lw_self), refreshed after every renorm/exchange

    // W0A already contains the adj factor (folded off the dependent chain).
#define STEP(W0A, W1) do {                    \
        const float sh = wave_shr1(p1);       \
        p1 = fmaf(p0, (W1), p1);              \
        p0 = fmaf(sh, (W0A), p0);             \
    } while (0)

#define QSTEP(WA, WB) do {                    \
        STEP(WA.x * adj, WB.x);               \
        STEP(WA.y * adj, WB.y);               \
        STEP(WA.z * adj, WB.z);               \
        STEP(WA.w * adj, WB.w);               \
    } while (0)

    // ---------------- main loop: 125 chunks of 16 steps ----------------
    for (int c = 0; c < 125; ++c) {
        if (c > 0) {
            if ((c & 3) == 0) {
                // ---- cross-wave exchange every 64 steps (log2 domain) ----
                __syncthreads();
                if (owned) {
                    Gbuf[64 + s0] = (p0 > 0.f) ? __builtin_amdgcn_logf(p0) + Lw : LOG0;
                    Gbuf[64 + s1] = (p1 > 0.f) ? __builtin_amdgcn_logf(p1) + Lw : LOG0;
                }
                __syncthreads();
                const float g0 = Gbuf[64 + s0];
                const float g1 = Gbuf[64 + s1];
                const float ref = fmaxf(g0, g1);
                const bool alive = (ref > 0.5f * LOG0);
                // live states form a prefix of the window -> last live lane is
                // nearest-live-left for all dead lanes. Uniform mask -> scalar ops.
                const unsigned long long mk = __ballot(alive);
                float fb = 0.f;
                if (mk) {
                    const int lastlive = 63 - __builtin_clzll(mk);
                    fb = __int_as_float(
                        __builtin_amdgcn_readlane(__float_as_int(ref), lastlive));
                }
                Lw = alive ? ref : fb;
                p0 = __builtin_amdgcn_exp2f(g0 - Lw);   // dead: exp2(-1e30)=0
                p1 = __builtin_amdgcn_exp2f(g1 - Lw);
            } else {
                // ---- per-lane renorm every 16 steps ----
                const float m = fmaxf(p0, p1);
                if (m > 0.f) {
                    const float inv = __builtin_amdgcn_rcpf(m);
                    Lw += __builtin_amdgcn_logf(m);     // v_log_f32 = log2
                    p0 *= inv; p1 *= inv;
                }
            }
            const float Lwp = wave_shr1(Lw);            // lane 0: Lwp=0; its sh inflow is 0 anyway
            adj = __builtin_amdgcn_exp2f(fminf(Lwp - Lw, 100.f));
        }
        const int tb = c << 4;
        {
            const float4 a0 = *reinterpret_cast<const float4*>(wrow0 + tb);
            const float4 a1 = *reinterpret_cast<const float4*>(wrow0 + tb + 4);
            const float4 a2 = *reinterpret_cast<const float4*>(wrow0 + tb + 8);
            const float4 a3 = *reinterpret_cast<const float4*>(wrow0 + tb + 12);
            const float4 b0 = *reinterpret_cast<const float4*>(wrow1 + tb);
            const float4 b1 = *reinterpret_cast<const float4*>(wrow1 + tb + 4);
            const float4 b2 = *reinterpret_cast<const float4*>(wrow1 + tb + 8);
            const float4 b3 = *reinterpret_cast<const float4*>(wrow1 + tb + 12);
            QSTEP(a0, b0);
            QSTEP(a1, b1);
            QSTEP(a2, b2);
            QSTEP(a3, b3);
        }
    }
#undef QSTEP
#undef STEP

    // ---------------- final write-out ----------------
    __syncthreads();
    if (owned) {
        Gbuf[64 + s0] = (p0 > 0.f) ? __builtin_amdgcn_logf(p0) + Lw : LOG0;
        Gbuf[64 + s1] = (p1 > 0.f) ? __builtin_amdgcn_logf(p1) + Lw : LOG0;
    }
    __syncthreads();
    if (tid == 0) {
        const int sl = seqlens[b];
        out[b] = -(Gbuf[64 + sl] * LN2F + red[0]) * (1.0f / (float)NT);
    }
}

extern "C" void kernel_launch(void* const* d_in, const int* in_sizes, int n_in,
                              void* d_out, int out_size, void* d_ws, size_t ws_size,
                              hipStream_t stream) {
    const float* x       = (const float*)d_in[0];
    const int*   seqs    = (const int*)d_in[1];
    const int*   seqlens = (const int*)d_in[2];
    float*       out     = (float*)d_out;

    ctc_fwd_kernel<<<dim3(NB), dim3(512), 0, stream>>>(x, seqs, seqlens, out);
}